// Round 21
// baseline (190.024 us; speedup 1.0000x reference)
//
#include <hip/hip_runtime.h>
#include <hip/hip_bf16.h>

#define D 512            // d_in == d_out == 512
#define NROWS 65536      // output rows
#define NBINS 256        // bins by row>>8
#define RPB 256          // rows per bin
#define P1B 1024         // nnz per phase-1 scatter block
#define SEGCAP 16        // per (blk,bin) segment capacity
#define MAXBLK1 512      // max phase-1 scatter blocks (nnz <= 524288)
#define BINCAP 2816      // per-bin pair capacity (lambda=2048, +17 sigma)
#define OVFCAP 4096      // overflow spill capacity

typedef float f32x4 __attribute__((ext_vector_type(4)));

// ---------- phase 1 (R15 exact): transpose (blocks 0..255) + LDS-binned scatter ----------
__global__ __launch_bounds__(256) void k_phase1(const float* __restrict__ w,
                                                __hip_bfloat16* __restrict__ wt,
                                                const int* __restrict__ rows,
                                                const int* __restrict__ cols,
                                                const float* __restrict__ vals, int nnz, int nblk1,
                                                uint2* __restrict__ gBin, int* __restrict__ gBinCnt,
                                                int* __restrict__ ovf_cnt, uint4* __restrict__ ovf) {
    int b = blockIdx.x, t = threadIdx.x;
    if (b < 256) {                               // weight transpose -> bf16 wT
        __shared__ float tile[32][33];
        int bx = b & 15, by = b >> 4;
        int tx = t & 31, ty = t >> 5;            // 32 x 8
        for (int i = ty; i < 32; i += 8)
            tile[i][tx] = w[(by * 32 + i) * D + bx * 32 + tx];
        __syncthreads();
        for (int i = ty; i < 32; i += 8)
            wt[(bx * 32 + i) * D + by * 32 + tx] = __float2bfloat16(tile[tx][i]);
        return;
    }
    __shared__ int  binCnt[NBINS];
    __shared__ uint2 binBuf[NBINS][SEGCAP];      // 32 KB
    b -= 256;
    binCnt[t] = 0;
    __syncthreads();
    int base = b * P1B;
    int end = base + P1B; if (end > nnz) end = nnz;
    for (int i = base + t; i < end; i += 256) {  // coalesced COO read
        int r = rows[i], c = cols[i];
        unsigned vb = __float_as_uint(vals[i]);
        int bin = r >> 8;
        int pos = atomicAdd(&binCnt[bin], 1);    // LDS atomic
        if (pos < SEGCAP) {
            binBuf[bin][pos] = make_uint2(((unsigned)r << 9) | (unsigned)c, vb);
        } else {                                 // rare (ovf_cnt pre-zeroed by memset)
            int o = atomicAdd(ovf_cnt, 1);
            if (o < OVFCAP) ovf[o] = make_uint4((unsigned)r, (unsigned)c, vb, 0u);
        }
    }
    __syncthreads();
    for (int idx = t; idx < NBINS * SEGCAP; idx += 256) {
        int bin = idx >> 4, slot = idx & (SEGCAP - 1);
        int cnt = binCnt[bin]; if (cnt > SEGCAP) cnt = SEGCAP;
        if (slot < cnt)
            gBin[((size_t)b * NBINS + bin) * SEGCAP + slot] = binBuf[bin][slot];
        if (slot == 0) gBinCnt[b * NBINS + bin] = cnt;
    }
}

// unpack one bf16x8 gather and accumulate
#define ACC8(wb, vv)                                   \
    do {                                               \
        f32x4 w0, w1;                                  \
        w0.x = __uint_as_float((wb).x << 16);          \
        w0.y = __uint_as_float((wb).x & 0xffff0000u);  \
        w0.z = __uint_as_float((wb).y << 16);          \
        w0.w = __uint_as_float((wb).y & 0xffff0000u);  \
        w1.x = __uint_as_float((wb).z << 16);          \
        w1.y = __uint_as_float((wb).z & 0xffff0000u);  \
        w1.z = __uint_as_float((wb).w << 16);          \
        w1.w = __uint_as_float((wb).w & 0xffff0000u);  \
        a0 += (vv) * w0;                               \
        a1 += (vv) * w1;                               \
    } while (0)

// ---------- R15-exact fused CSR-build + spmm (1024 thr, Hillis-Steele scans) ----------
__global__ __launch_bounds__(1024) void k_binspmm(const uint2* __restrict__ gBin,
                                                  const int* __restrict__ gBinCnt, int nblk1,
                                                  const uint4* __restrict__ wt4,
                                                  const f32x4* __restrict__ bias4,
                                                  f32x4* __restrict__ out,
                                                  int* __restrict__ ovf_cnt,
                                                  uint4* __restrict__ ovf) {
    __shared__ int segCnt[MAXBLK1], segOff[MAXBLK1], scanBuf[MAXBLK1];
    __shared__ int rowCnt[RPB], rowOff[RPB], cursor[RPB];
    __shared__ uint2 pairBuf[BINCAP];
    __shared__ uint2 csrBuf[BINCAP];
    __shared__ int totalPairs;
    int bin = blockIdx.x, t = threadIdx.x;
    int sc = (t < nblk1) ? gBinCnt[t * NBINS + bin] : 0;
    if (t < MAXBLK1) scanBuf[t] = sc;
    if (t < RPB) rowCnt[t] = 0;
    __syncthreads();
    for (int off = 1; off < MAXBLK1; off <<= 1) {
        int x = (t < MAXBLK1 && t >= off) ? scanBuf[t - off] : 0;
        __syncthreads();
        if (t < MAXBLK1) scanBuf[t] += x;
        __syncthreads();
    }
    if (t < MAXBLK1) { segOff[t] = scanBuf[t] - sc; segCnt[t] = sc; }
    if (t == MAXBLK1 - 1) totalPairs = scanBuf[MAXBLK1 - 1];
    __syncthreads();
    int total = totalPairs; if (total > BINCAP) total = BINCAP;
    for (int idx = t; idx < nblk1 * SEGCAP; idx += 1024) {
        int blk = idx >> 4, slot = idx & (SEGCAP - 1);
        if (slot < segCnt[blk]) {
            int dst = segOff[blk] + slot;
            uint2 p = gBin[((size_t)blk * NBINS + bin) * SEGCAP + slot];
            if (dst < BINCAP) {
                pairBuf[dst] = p;
                atomicAdd(&rowCnt[(p.x >> 9) & (RPB - 1)], 1);
            } else {
                int o = atomicAdd(ovf_cnt, 1);
                if (o < OVFCAP)
                    ovf[o] = make_uint4(p.x >> 9, p.x & 511u, p.y, 0u);
            }
        }
    }
    __syncthreads();
    int rc = (t < RPB) ? rowCnt[t] : 0;
    if (t < RPB) scanBuf[t] = rc;
    __syncthreads();
    for (int off = 1; off < RPB; off <<= 1) {
        int x = (t < RPB && t >= off) ? scanBuf[t - off] : 0;
        __syncthreads();
        if (t < RPB) scanBuf[t] += x;
        __syncthreads();
    }
    if (t < RPB) { rowOff[t] = scanBuf[t] - rc; cursor[t] = scanBuf[t] - rc; }
    __syncthreads();
    for (int k = t; k < total; k += 1024) {
        uint2 p = pairBuf[k];
        int r = (p.x >> 9) & (RPB - 1);
        int pos = atomicAdd(&cursor[r], 1);
        csrBuf[pos] = make_uint2(p.x & 511u, p.y);
    }
    __syncthreads();
    int wv = t >> 6, lane = t & 63;
    f32x4 bb0 = bias4[lane * 2];
    f32x4 bb1 = bias4[lane * 2 + 1];
    int novf = *ovf_cnt;
    if (novf > OVFCAP) novf = OVFCAP;
    for (int rloc = wv; rloc < RPB; rloc += 16) {
        int cnt = rowCnt[rloc], o = rowOff[rloc];
        f32x4 a0 = bb0, a1 = bb1;
        for (int s = 0; s < cnt; s += 4) {
            int i1 = (s + 1 < cnt) ? s + 1 : s;
            int i2 = (s + 2 < cnt) ? s + 2 : s;
            int i3 = (s + 3 < cnt) ? s + 3 : s;
            uint2 p0 = csrBuf[o + s];
            uint2 p1 = csrBuf[o + i1];
            uint2 p2 = csrBuf[o + i2];
            uint2 p3 = csrBuf[o + i3];
            float v0 = __uint_as_float(p0.y);
            float v1 = (s + 1 < cnt) ? __uint_as_float(p1.y) : 0.f;
            float v2 = (s + 2 < cnt) ? __uint_as_float(p2.y) : 0.f;
            float v3 = (s + 3 < cnt) ? __uint_as_float(p3.y) : 0.f;
            uint4 wb0 = wt4[(size_t)p0.x * 64 + lane];
            uint4 wb1 = wt4[(size_t)p1.x * 64 + lane];
            uint4 wb2 = wt4[(size_t)p2.x * 64 + lane];
            uint4 wb3 = wt4[(size_t)p3.x * 64 + lane];
            ACC8(wb0, v0);
            ACC8(wb1, v1);
            ACC8(wb2, v2);
            ACC8(wb3, v3);
        }
        int row = (bin << 8) + rloc;
        if (novf > 0) {
            for (int e = 0; e < novf; ++e) {
                uint4 p = ovf[e];
                if ((int)p.x == row) {
                    float v = __uint_as_float(p.z);
                    uint4 wb = wt4[(size_t)p.y * 64 + lane];
                    ACC8(wb, v);
                }
            }
        }
        f32x4* op = out + (size_t)row * (D / 4);
        op[lane * 2]     = a0;
        op[lane * 2 + 1] = a1;
    }
}

// ---------- fallback path (tiny workspace) ----------
__global__ void k_init_bias(const float* __restrict__ bias, float* __restrict__ out, int total) {
    int i = blockIdx.x * blockDim.x + threadIdx.x;
    if (i < total) out[i] = bias[i & (D - 1)];
}

__global__ void k_atomic_spmm(const int* __restrict__ rows, const int* __restrict__ cols,
                              const float* __restrict__ vals, int nnz,
                              const float* __restrict__ w, float* __restrict__ out) {
    int wid = (int)((blockIdx.x * blockDim.x + threadIdx.x) >> 6);
    if (wid >= nnz) return;
    int lane = threadIdx.x & 63;
    int r = rows[wid];
    int c = cols[wid];
    float v = vals[wid];
    float* op = out + (size_t)r * D + lane * 8;
#pragma unroll
    for (int k = 0; k < 8; ++k) {
        float wv = w[(size_t)(lane * 8 + k) * D + c];
        atomicAdd(&op[k], v * wv);
    }
}

extern "C" void kernel_launch(void* const* d_in, const int* in_sizes, int n_in,
                              void* d_out, int out_size, void* d_ws, size_t ws_size,
                              hipStream_t stream) {
    const int*   rows   = (const int*)d_in[0];
    const int*   cols   = (const int*)d_in[1];
    const float* vals   = (const float*)d_in[2];
    const float* weight = (const float*)d_in[3];
    const float* bias   = (const float*)d_in[4];
    float*       out    = (float*)d_out;
    const int nnz = in_sizes[0];
    const int nblk1 = (nnz + P1B - 1) / P1B;

    // workspace carve-out
    char* ws = (char*)d_ws;
    size_t off = 0;
    auto alloc = [&](size_t bytes) -> void* {
        off = (off + 255) & ~(size_t)255;
        void* p = ws + off;
        off += bytes;
        return p;
    };
    __hip_bfloat16* wT = (__hip_bfloat16*)alloc((size_t)D * D * sizeof(__hip_bfloat16)); // 512 KiB
    int*   ovf_cnt = (int*)  alloc(256);
    uint4* ovf     = (uint4*)alloc((size_t)OVFCAP * sizeof(uint4));                      // 64 KiB
    uint2* gBin    = (uint2*)alloc((size_t)MAXBLK1 * NBINS * SEGCAP * sizeof(uint2));    // 16 MiB
    int*   gBinCnt = (int*)  alloc((size_t)MAXBLK1 * NBINS * sizeof(int));               // 512 KiB
    const size_t need_full = off;

    if (need_full <= ws_size && nblk1 <= MAXBLK1) {
        // ---- DIAGNOSTIC: R15 pipeline, binspmm x4 (idempotent). dur = P + 4*S; R15: P+S=57.8 ----
        hipMemsetAsync(ovf_cnt, 0, sizeof(int), stream);
        k_phase1<<<256 + nblk1, 256, 0, stream>>>(weight, wT, rows, cols, vals, nnz, nblk1,
                                                  gBin, gBinCnt, ovf_cnt, ovf);
        for (int rep = 0; rep < 4; ++rep) {
            k_binspmm<<<NBINS, 1024, 0, stream>>>(gBin, gBinCnt, nblk1, (const uint4*)wT,
                                                  (const f32x4*)bias, (f32x4*)out, ovf_cnt, ovf);
        }
    } else {
        // ---- atomic fallback ----
        k_init_bias<<<(out_size + 255) / 256, 256, 0, stream>>>(bias, out, out_size);
        k_atomic_spmm<<<((size_t)nnz * 64 + 255) / 256, 256, 0, stream>>>(rows, cols, vals, nnz, weight, out);
    }
}

// Round 22
// 59.609 us; speedup vs baseline: 3.1878x; 3.1878x over previous
//
#include <hip/hip_runtime.h>
#include <hip/hip_bf16.h>

#define D 512            // d_in == d_out == 512
#define NROWS 65536      // output rows
#define NBINS 256        // bins by row>>8
#define RPB 256          // rows per bin
#define P1B 1024         // nnz per phase-1 scatter block
#define SEGCAP 16        // per (blk,bin) segment capacity
#define MAXBLK1 512      // max phase-1 scatter blocks (nnz <= 524288)
#define RCAP 32          // per-row slot capacity (Poisson mean 8; P(>32)~1e-12)
#define OVFCAP 4096      // overflow spill capacity

typedef float f32x4 __attribute__((ext_vector_type(4)));

// ---------- phase 1 (R15 exact): transpose (blocks 0..255) + LDS-binned scatter ----------
__global__ __launch_bounds__(256) void k_phase1(const float* __restrict__ w,
                                                __hip_bfloat16* __restrict__ wt,
                                                const int* __restrict__ rows,
                                                const int* __restrict__ cols,
                                                const float* __restrict__ vals, int nnz, int nblk1,
                                                uint2* __restrict__ gBin, int* __restrict__ gBinCnt,
                                                int* __restrict__ ovf_cnt, uint4* __restrict__ ovf) {
    int b = blockIdx.x, t = threadIdx.x;
    if (b < 256) {                               // weight transpose -> bf16 wT
        __shared__ float tile[32][33];
        int bx = b & 15, by = b >> 4;
        int tx = t & 31, ty = t >> 5;            // 32 x 8
        for (int i = ty; i < 32; i += 8)
            tile[i][tx] = w[(by * 32 + i) * D + bx * 32 + tx];
        __syncthreads();
        for (int i = ty; i < 32; i += 8)
            wt[(bx * 32 + i) * D + by * 32 + tx] = __float2bfloat16(tile[tx][i]);
        return;
    }
    __shared__ int  binCnt[NBINS];
    __shared__ uint2 binBuf[NBINS][SEGCAP];      // 32 KB
    b -= 256;
    binCnt[t] = 0;
    __syncthreads();
    int base = b * P1B;
    int end = base + P1B; if (end > nnz) end = nnz;
    for (int i = base + t; i < end; i += 256) {  // coalesced COO read
        int r = rows[i], c = cols[i];
        unsigned vb = __float_as_uint(vals[i]);
        int bin = r >> 8;
        int pos = atomicAdd(&binCnt[bin], 1);    // LDS atomic
        if (pos < SEGCAP) {
            binBuf[bin][pos] = make_uint2(((unsigned)r << 9) | (unsigned)c, vb);
        } else {                                 // rare (ovf_cnt pre-zeroed by memset)
            int o = atomicAdd(ovf_cnt, 1);
            if (o < OVFCAP) ovf[o] = make_uint4((unsigned)r, (unsigned)c, vb, 0u);
        }
    }
    __syncthreads();
    for (int idx = t; idx < NBINS * SEGCAP; idx += 256) {
        int bin = idx >> 4, slot = idx & (SEGCAP - 1);
        int cnt = binCnt[bin]; if (cnt > SEGCAP) cnt = SEGCAP;
        if (slot < cnt)
            gBin[((size_t)b * NBINS + bin) * SEGCAP + slot] = binBuf[bin][slot];
        if (slot == 0) gBinCnt[b * NBINS + bin] = cnt;
    }
}

// unpack one bf16x8 gather and accumulate
#define ACC8(wb, vv)                                   \
    do {                                               \
        f32x4 w0, w1;                                  \
        w0.x = __uint_as_float((wb).x << 16);          \
        w0.y = __uint_as_float((wb).x & 0xffff0000u);  \
        w0.z = __uint_as_float((wb).y << 16);          \
        w0.w = __uint_as_float((wb).y & 0xffff0000u);  \
        w1.x = __uint_as_float((wb).z << 16);          \
        w1.y = __uint_as_float((wb).z & 0xffff0000u);  \
        w1.z = __uint_as_float((wb).w << 16);          \
        w1.w = __uint_as_float((wb).w & 0xffff0000u);  \
        a0 += (vv) * w0;                               \
        a1 += (vv) * w1;                               \
    } while (0)

// ---------- fused build+spmm: ONE build pass, ONE barrier ----------
// gather gBin pairs directly into fixed per-row LDS slots; no scans, no pairBuf/csrBuf.
__global__ __launch_bounds__(1024) void k_binspmm(const uint2* __restrict__ gBin,
                                                  const int* __restrict__ gBinCnt, int nblk1,
                                                  const uint4* __restrict__ wt4,   // bf16 wT
                                                  const f32x4* __restrict__ bias4,
                                                  f32x4* __restrict__ out,
                                                  int* __restrict__ ovf_cnt,
                                                  uint4* __restrict__ ovf) {
    __shared__ int  segCnt[MAXBLK1];             // 2 KB
    __shared__ int  cursor[RPB];                 // 1 KB
    __shared__ uint2 rowBuf[RPB][RCAP];          // 64 KB
    int bin = blockIdx.x, t = threadIdx.x;
    int wv = t >> 6, lane = t & 63;
    // 1) init
    if (t < MAXBLK1) segCnt[t] = (t < nblk1) ? gBinCnt[t * NBINS + bin] : 0;
    if (t < RPB) cursor[t] = 0;
    __syncthreads();
    // 2) single gather pass: gBin -> per-row LDS slots
    for (int idx = t; idx < nblk1 * SEGCAP; idx += 1024) {
        int blk = idx >> 4, slot = idx & (SEGCAP - 1);
        if (slot < segCnt[blk]) {
            uint2 p = gBin[((size_t)blk * NBINS + bin) * SEGCAP + slot];
            int r = (int)(p.x >> 9) & (RPB - 1);
            int pos = atomicAdd(&cursor[r], 1);
            if (pos < RCAP) {
                rowBuf[r][pos] = make_uint2(p.x & 511u, p.y);
            } else {                             // P ~ 1e-12 per row
                int o = atomicAdd(ovf_cnt, 1);
                if (o < OVFCAP)
                    ovf[o] = make_uint4(p.x >> 9, p.x & 511u, p.y, 0u);
            }
        }
    }
    __syncthreads();
    // 3) spmm: 16 waves x 16 rows each, pairs broadcast-read from rowBuf
    f32x4 bb0 = bias4[lane * 2];
    f32x4 bb1 = bias4[lane * 2 + 1];
    int novf = *ovf_cnt;
    if (novf > OVFCAP) novf = OVFCAP;
    for (int rloc = wv; rloc < RPB; rloc += 16) {
        int cnt = cursor[rloc]; if (cnt > RCAP) cnt = RCAP;
        f32x4 a0 = bb0, a1 = bb1;
        for (int s = 0; s < cnt; s += 4) {       // 4 gathers in flight
            int i1 = (s + 1 < cnt) ? s + 1 : s;
            int i2 = (s + 2 < cnt) ? s + 2 : s;
            int i3 = (s + 3 < cnt) ? s + 3 : s;
            uint2 p0 = rowBuf[rloc][s];
            uint2 p1 = rowBuf[rloc][i1];
            uint2 p2 = rowBuf[rloc][i2];
            uint2 p3 = rowBuf[rloc][i3];
            float v0 = __uint_as_float(p0.y);
            float v1 = (s + 1 < cnt) ? __uint_as_float(p1.y) : 0.f;
            float v2 = (s + 2 < cnt) ? __uint_as_float(p2.y) : 0.f;
            float v3 = (s + 3 < cnt) ? __uint_as_float(p3.y) : 0.f;
            uint4 wb0 = wt4[(size_t)p0.x * 64 + lane];
            uint4 wb1 = wt4[(size_t)p1.x * 64 + lane];
            uint4 wb2 = wt4[(size_t)p2.x * 64 + lane];
            uint4 wb3 = wt4[(size_t)p3.x * 64 + lane];
            ACC8(wb0, v0);
            ACC8(wb1, v1);
            ACC8(wb2, v2);
            ACC8(wb3, v3);
        }
        int row = (bin << 8) + rloc;
        if (novf > 0) {                          // rare spill path
            for (int e = 0; e < novf; ++e) {
                uint4 p = ovf[e];
                if ((int)p.x == row) {
                    float v = __uint_as_float(p.z);
                    uint4 wb = wt4[(size_t)p.y * 64 + lane];
                    ACC8(wb, v);
                }
            }
        }
        f32x4* op = out + (size_t)row * (D / 4);
        op[lane * 2]     = a0;
        op[lane * 2 + 1] = a1;
    }
}

// ---------- fallback path (tiny workspace) ----------
__global__ void k_init_bias(const float* __restrict__ bias, float* __restrict__ out, int total) {
    int i = blockIdx.x * blockDim.x + threadIdx.x;
    if (i < total) out[i] = bias[i & (D - 1)];
}

__global__ void k_atomic_spmm(const int* __restrict__ rows, const int* __restrict__ cols,
                              const float* __restrict__ vals, int nnz,
                              const float* __restrict__ w, float* __restrict__ out) {
    int wid = (int)((blockIdx.x * blockDim.x + threadIdx.x) >> 6);
    if (wid >= nnz) return;
    int lane = threadIdx.x & 63;
    int r = rows[wid];
    int c = cols[wid];
    float v = vals[wid];
    float* op = out + (size_t)r * D + lane * 8;
#pragma unroll
    for (int k = 0; k < 8; ++k) {
        float wv = w[(size_t)(lane * 8 + k) * D + c];
        atomicAdd(&op[k], v * wv);
    }
}

extern "C" void kernel_launch(void* const* d_in, const int* in_sizes, int n_in,
                              void* d_out, int out_size, void* d_ws, size_t ws_size,
                              hipStream_t stream) {
    const int*   rows   = (const int*)d_in[0];
    const int*   cols   = (const int*)d_in[1];
    const float* vals   = (const float*)d_in[2];
    const float* weight = (const float*)d_in[3];
    const float* bias   = (const float*)d_in[4];
    float*       out    = (float*)d_out;
    const int nnz = in_sizes[0];
    const int nblk1 = (nnz + P1B - 1) / P1B;

    // workspace carve-out
    char* ws = (char*)d_ws;
    size_t off = 0;
    auto alloc = [&](size_t bytes) -> void* {
        off = (off + 255) & ~(size_t)255;
        void* p = ws + off;
        off += bytes;
        return p;
    };
    __hip_bfloat16* wT = (__hip_bfloat16*)alloc((size_t)D * D * sizeof(__hip_bfloat16)); // 512 KiB
    int*   ovf_cnt = (int*)  alloc(256);
    uint4* ovf     = (uint4*)alloc((size_t)OVFCAP * sizeof(uint4));                      // 64 KiB
    uint2* gBin    = (uint2*)alloc((size_t)MAXBLK1 * NBINS * SEGCAP * sizeof(uint2));    // 16 MiB
    int*   gBinCnt = (int*)  alloc((size_t)MAXBLK1 * NBINS * sizeof(int));               // 512 KiB
    const size_t need_full = off;

    if (need_full <= ws_size && nblk1 <= MAXBLK1) {
        // ---- 2 dispatches (+4B memset): binned scatter -> single-pass build + spmm ----
        hipMemsetAsync(ovf_cnt, 0, sizeof(int), stream);
        k_phase1<<<256 + nblk1, 256, 0, stream>>>(weight, wT, rows, cols, vals, nnz, nblk1,
                                                  gBin, gBinCnt, ovf_cnt, ovf);
        k_binspmm<<<NBINS, 1024, 0, stream>>>(gBin, gBinCnt, nblk1, (const uint4*)wT,
                                              (const f32x4*)bias, (f32x4*)out, ovf_cnt, ovf);
    } else {
        // ---- atomic fallback ----
        k_init_bias<<<(out_size + 255) / 256, 256, 0, stream>>>(bias, out, out_size);
        k_atomic_spmm<<<((size_t)nnz * 64 + 255) / 256, 256, 0, stream>>>(rows, cols, vals, nnz, weight, out);
    }
}